// Round 1
// baseline (67.641 us; speedup 1.0000x reference)
//
#include <hip/hip_runtime.h>

#define BATCH   4
#define NCUR    8192
#define NSUR    24576
#define NPTS    (NCUR + NSUR)          // 32768 points per batch
#define NPATCH  64                     // B * 16
#define GS      18
#define LS      36
#define GVOL    (GS*GS*GS)             // 5832
#define LVOL    (LS*LS*LS)             // 46656
#define GOUT_TOTAL (NPATCH*2*GVOL)     // 746496

// ---------------------------------------------------------------------------
// Kernel 1: per-point MLP (3 -> 128 -> 16) + scatter winner index (atomicMax)
// ---------------------------------------------------------------------------
__global__ __launch_bounds__(256)
void mlp_scatter_kernel(const float* __restrict__ curves,
                        const float* __restrict__ surfaces,
                        const float* __restrict__ W1,
                        const float* __restrict__ b1,
                        const float* __restrict__ W2,
                        const float* __restrict__ b2,
                        int*   __restrict__ winner,   // (B,128,128,128), init -1
                        float* __restrict__ feat)     // (B,NPTS,16)
{
    __shared__ float sW1[384];   // (128,3)
    __shared__ float sb1[128];
    __shared__ float sW2[2048];  // (16,128)
    __shared__ float sb2[16];
    for (int t = threadIdx.x; t < 384;  t += 256) sW1[t] = W1[t];
    for (int t = threadIdx.x; t < 128;  t += 256) sb1[t] = b1[t];
    for (int t = threadIdx.x; t < 2048; t += 256) sW2[t] = W2[t];
    if (threadIdx.x < 16) sb2[threadIdx.x] = b2[threadIdx.x];
    __syncthreads();

    int gid = blockIdx.x * 256 + threadIdx.x;
    if (gid >= BATCH * NPTS) return;
    int b = gid / NPTS;
    int n = gid - b * NPTS;

    float x0, x1, x2;
    if (n < NCUR) {
        const float* p = curves + ((size_t)b * NCUR + n) * 3;
        x0 = p[0]; x1 = p[1]; x2 = p[2];
    } else {
        const float* p = surfaces + ((size_t)b * NSUR + (n - NCUR)) * 3;
        x0 = p[0]; x1 = p[1]; x2 = p[2];
    }

    float acc[16];
    #pragma unroll
    for (int o = 0; o < 16; ++o) acc[o] = sb2[o];

    #pragma unroll 4
    for (int c = 0; c < 128; ++c) {
        float h = fmaf(x2, sW1[c*3+2],
                  fmaf(x1, sW1[c*3+1],
                  fmaf(x0, sW1[c*3+0], sb1[c])));
        h = fmaxf(h, 0.0f);
        #pragma unroll
        for (int o = 0; o < 16; ++o)
            acc[o] = fmaf(h, sW2[o*128 + c], acc[o]);
    }

    float4* fo = (float4*)(feat + (size_t)gid * 16);
    fo[0] = make_float4(acc[0],  acc[1],  acc[2],  acc[3]);
    fo[1] = make_float4(acc[4],  acc[5],  acc[6],  acc[7]);
    fo[2] = make_float4(acc[8],  acc[9],  acc[10], acc[11]);
    fo[3] = make_float4(acc[12], acc[13], acc[14], acc[15]);

    // cell index: clip(x*128 + 64.5, 0, 127), truncate. Use non-fused mul/add
    // so rounding matches the numpy reference exactly at cell boundaries.
    float cx = fminf(fmaxf(__fadd_rn(__fmul_rn(x0, 128.0f), 64.5f), 0.0f), 127.0f);
    float cy = fminf(fmaxf(__fadd_rn(__fmul_rn(x1, 128.0f), 64.5f), 0.0f), 127.0f);
    float cz = fminf(fmaxf(__fadd_rn(__fmul_rn(x2, 128.0f), 64.5f), 0.0f), 127.0f);
    int ix = (int)cx, iy = (int)cy, iz = (int)cz;

    // last-write-wins over ascending n  ==  max point index wins
    atomicMax(winner + ((((size_t)b*128 + ix)*128 + iy)*128 + iz), n);
}

// ---------------------------------------------------------------------------
// Kernel 2: global patches (64, 2, 18,18,18) gathered from occ (B,2,64,64,64)
// with zero pad of 1 on each spatial side.
// ---------------------------------------------------------------------------
__global__ __launch_bounds__(256)
void global_patch_kernel(const float* __restrict__ occ,
                         const int*   __restrict__ indices,  // 64 flat
                         float* __restrict__ out)
{
    int gid = blockIdx.x * 256 + threadIdx.x;
    if (gid >= GOUT_TOTAL) return;
    int z = gid % 18;
    int y = (gid / 18) % 18;
    int x = (gid / 324) % 18;
    int c = (gid / GVOL) & 1;
    int q = gid / (2 * GVOL);

    int b = q >> 4;
    int p = indices[q];
    int i = p >> 4, j = (p >> 2) & 3, k = p & 3;

    int X = i*16 + x - 1;
    int Y = j*16 + y - 1;
    int Z = k*16 + z - 1;
    float v = 0.0f;
    if ((unsigned)X < 64u && (unsigned)Y < 64u && (unsigned)Z < 64u)
        v = occ[((((size_t)b*2 + c)*64 + X)*64 + Y)*64 + Z];
    out[gid] = v;
}

// ---------------------------------------------------------------------------
// Kernel 3: local patches (64, 16, 36,36,36). One thread per spatial element,
// loops over the 16 channels; one winner-index read serves all channels.
// ---------------------------------------------------------------------------
__global__ __launch_bounds__(256)
void local_patch_kernel(const int*   __restrict__ winner,
                        const float* __restrict__ feat,
                        const int*   __restrict__ indices,
                        float* __restrict__ out)   // points at local section
{
    int gid = blockIdx.x * 256 + threadIdx.x;
    if (gid >= NPATCH * LVOL) return;
    int q = gid / LVOL;
    int s = gid - q * LVOL;
    int z = s % 36;
    int y = (s / 36) % 36;
    int x = s / 1296;

    int b = q >> 4;
    int p = indices[q];
    int i = p >> 4, j = (p >> 2) & 3, k = p & 3;

    int X = i*32 + x - 2;
    int Y = j*32 + y - 2;
    int Z = k*32 + z - 2;

    int w = -1;
    if ((unsigned)X < 128u && (unsigned)Y < 128u && (unsigned)Z < 128u)
        w = winner[(((size_t)b*128 + X)*128 + Y)*128 + Z];

    float vals[16];
    if (w >= 0) {
        const float4* f = (const float4*)(feat + ((size_t)b*NPTS + w)*16);
        float4 a0 = f[0], a1 = f[1], a2 = f[2], a3 = f[3];
        vals[0]=a0.x;  vals[1]=a0.y;  vals[2]=a0.z;  vals[3]=a0.w;
        vals[4]=a1.x;  vals[5]=a1.y;  vals[6]=a1.z;  vals[7]=a1.w;
        vals[8]=a2.x;  vals[9]=a2.y;  vals[10]=a2.z; vals[11]=a2.w;
        vals[12]=a3.x; vals[13]=a3.y; vals[14]=a3.z; vals[15]=a3.w;
    } else {
        #pragma unroll
        for (int c = 0; c < 16; ++c) vals[c] = 0.0f;
    }

    size_t base = (size_t)q * 16 * LVOL + s;
    #pragma unroll
    for (int c = 0; c < 16; ++c)
        out[base + (size_t)c * LVOL] = vals[c];
}

// ---------------------------------------------------------------------------
extern "C" void kernel_launch(void* const* d_in, const int* in_sizes, int n_in,
                              void* d_out, int out_size, void* d_ws, size_t ws_size,
                              hipStream_t stream)
{
    const float* curves   = (const float*)d_in[0];
    const float* surfaces = (const float*)d_in[1];
    const float* occ      = (const float*)d_in[2];
    const int*   indices  = (const int*)  d_in[3];
    const float* W1       = (const float*)d_in[4];
    const float* b1       = (const float*)d_in[5];
    const float* W2       = (const float*)d_in[6];
    const float* b2       = (const float*)d_in[7];

    const size_t winner_bytes = (size_t)BATCH * 128 * 128 * 128 * sizeof(int); // 33.5 MB
    int*   winner = (int*)d_ws;
    float* feat   = (float*)((char*)d_ws + winner_bytes);                      // 8.4 MB

    // winner grid = -1 everywhere (0xFF bytes)
    hipMemsetAsync(winner, 0xFF, winner_bytes, stream);

    mlp_scatter_kernel<<<(BATCH*NPTS + 255)/256, 256, 0, stream>>>(
        curves, surfaces, W1, b1, W2, b2, winner, feat);

    global_patch_kernel<<<(GOUT_TOTAL + 255)/256, 256, 0, stream>>>(
        occ, indices, (float*)d_out);

    local_patch_kernel<<<(NPATCH*LVOL + 255)/256, 256, 0, stream>>>(
        winner, feat, indices, (float*)d_out + GOUT_TOTAL);
}